// Round 6
// baseline (353.073 us; speedup 1.0000x reference)
//
#include <hip/hip_runtime.h>

#define D_IN 512
#define D_OUT 256

typedef short short8 __attribute__((ext_vector_type(8)));
typedef float floatx4 __attribute__((ext_vector_type(4)));

static __device__ __forceinline__ unsigned short f2bf(float f) {
    unsigned u = __float_as_uint(f);
    u += 0x7FFF + ((u >> 16) & 1);
    return (unsigned short)(u >> 16);
}
static __device__ __forceinline__ float bf2f(unsigned short h) {
    return __uint_as_float((unsigned)h << 16);
}

// ---------------- prep: convert W + zero cnt (one dispatch) ----------------
__global__ __launch_bounds__(256) void prep(const float* __restrict__ W,
                                            unsigned short* __restrict__ Wt,
                                            int* __restrict__ cnt, int M) {
    int b = blockIdx.x;
    if (b < 512) {
        int t = b * 256 + threadIdx.x;
        int n = t >> 9;
        int k = t & 511;
        Wt[t] = f2bf(W[(size_t)k * D_OUT + n]);
    } else {
        int i = (b - 512) * 256 + threadIdx.x;
        if (i < M) cnt[i] = 0;
    }
}

// ---------------- GEMM: S(bf16) = bf16(A) @ bf16(W), fp32 accum ----------------
// 512 threads = 8 waves; wave w owns rows [bm+w*16, bm+w*16+16), all 128 n of bn.
// A read DIRECT from global per-lane (each wave owns distinct rows -> converted once).
// B (pre-converted bf16 Wt, L2-hot) staged through LDS in 64-k chunks.
#define LDB 72   // chunk row stride (elems); 144 B rows, 16B-aligned
__global__ __launch_bounds__(512) void gemm_bf16(const float* __restrict__ A,
                                                 const unsigned short* __restrict__ Wt,
                                                 unsigned short* __restrict__ S, int M) {
    __shared__ unsigned short Bs[128 * LDB];   // 18.4 KB
    const int tid  = threadIdx.x;
    const int lane = tid & 63;
    const int w    = tid >> 6;
    const int l15  = lane & 15;
    const int quad = lane >> 4;
    const int bm   = blockIdx.x * 128;
    const int bn   = blockIdx.y * 128;
    const int row  = bm + w * 16 + l15;
    const float* arow = A + (size_t)(row < M ? row : 0) * D_IN;

    // B staging: 2 items x 16B (short8) per thread per chunk
    int sn[2], sk[2];
#pragma unroll
    for (int i = 0; i < 2; ++i) {
        int idx = tid + i * 512;       // 0..1023
        sn[i] = idx >> 3;              // 0..127
        sk[i] = (idx & 7) * 8;         // 0..56
    }

    floatx4 acc[8] = {};

    for (int kc = 0; kc < D_IN; kc += 64) {
        __syncthreads();   // protect Bs overwrite (prev chunk fully consumed)
#pragma unroll
        for (int i = 0; i < 2; ++i)
            *(short8*)(Bs + sn[i] * LDB + sk[i]) =
                *(const short8*)(Wt + (size_t)(bn + sn[i]) * D_IN + kc + sk[i]);
        __syncthreads();

#pragma unroll
        for (int kk = 0; kk < 64; kk += 32) {
            // A fragment: row l15 (of wave's 16), k = kc+kk+quad*8 .. +8, fp32 direct
            float4 a0 = *(const float4*)(arow + kc + kk + quad * 8);
            float4 a1 = *(const float4*)(arow + kc + kk + quad * 8 + 4);
            short8 af;
            af[0] = (short)f2bf(a0.x); af[1] = (short)f2bf(a0.y);
            af[2] = (short)f2bf(a0.z); af[3] = (short)f2bf(a0.w);
            af[4] = (short)f2bf(a1.x); af[5] = (short)f2bf(a1.y);
            af[6] = (short)f2bf(a1.z); af[7] = (short)f2bf(a1.w);
#pragma unroll
            for (int j = 0; j < 8; ++j) {
                short8 bf = *(const short8*)(Bs + (j * 16 + l15) * LDB + kk + quad * 8);
                acc[j] = __builtin_amdgcn_mfma_f32_16x16x32_bf16(af, bf, acc[j], 0, 0, 0);
            }
        }
    }

    // epilogue: C row = w*16 + quad*4 + r, col = j*16 + l15
#pragma unroll
    for (int r = 0; r < 4; ++r) {
        int gm = bm + w * 16 + quad * 4 + r;
        if (gm < M) {
#pragma unroll
            for (int j = 0; j < 8; ++j)
                S[(size_t)gm * D_OUT + bn + j * 16 + l15] = f2bf(acc[j][r]);
        }
    }
}

// ---------------- histogram (separate: random atomics must not share a dispatch
// with the streaming gemm — r5 showed 40us contention regression) ----------------
__global__ __launch_bounds__(256) void hist_rows(const int* __restrict__ rows,
                                                 int* __restrict__ cnt, int E4) {
    int t = blockIdx.x * 256 + threadIdx.x;
    if (t < E4) {
        int4 r = ((const int4*)rows)[t];
        atomicAdd(&cnt[r.x], 1);
        atomicAdd(&cnt[r.y], 1);
        atomicAdd(&cnt[r.z], 1);
        atomicAdd(&cnt[r.w], 1);
    }
}

// ---------------- scan: cnt -> ptr (exclusive), fill = ptr copy ----------------
__global__ __launch_bounds__(1024) void scan_rowptr(const int* __restrict__ cnt,
                                                    int* __restrict__ ptr,
                                                    int* __restrict__ fill, int M) {
    __shared__ int wsum[16];
    __shared__ int sh_carry;
    const int t = threadIdx.x, lane = t & 63, wave = t >> 6;
    if (t == 0) sh_carry = 0;
    __syncthreads();
    for (int base0 = 0; base0 < M; base0 += 4096) {
        int base = base0 + t * 4;
        int4 v = make_int4(0, 0, 0, 0);
        if (base + 3 < M) v = *(const int4*)(cnt + base);
        else {
            if (base + 0 < M) v.x = cnt[base + 0];
            if (base + 1 < M) v.y = cnt[base + 1];
            if (base + 2 < M) v.z = cnt[base + 2];
        }
        int s = v.x + v.y + v.z + v.w;
        int incl = s;
#pragma unroll
        for (int off = 1; off < 64; off <<= 1) {
            int x = __shfl_up(incl, off, 64);
            if (lane >= off) incl += x;
        }
        if (lane == 63) wsum[wave] = incl;
        __syncthreads();
        if (t == 0) {
            int run = sh_carry;
#pragma unroll
            for (int wv = 0; wv < 16; ++wv) { int x = wsum[wv]; wsum[wv] = run; run += x; }
            sh_carry = run;
        }
        __syncthreads();
        int e0 = wsum[wave] + (incl - s);
        int e1 = e0 + v.x, e2 = e1 + v.y, e3 = e2 + v.z;
        if (base + 3 < M) {
            *(int4*)(ptr + base)  = make_int4(e0, e1, e2, e3);
            *(int4*)(fill + base) = make_int4(e0, e1, e2, e3);
        } else {
            if (base + 0 < M) { ptr[base + 0] = e0; fill[base + 0] = e0; }
            if (base + 1 < M) { ptr[base + 1] = e1; fill[base + 1] = e1; }
            if (base + 2 < M) { ptr[base + 2] = e2; fill[base + 2] = e2; }
        }
        __syncthreads();
    }
    if (t == 0) ptr[M] = sh_carry;
}

// ---------------- place edges at sorted positions ----------------
__global__ __launch_bounds__(256) void build_sorted(const float* __restrict__ vals,
                                                    const int* __restrict__ rows,
                                                    const int* __restrict__ cols,
                                                    int* __restrict__ fill,
                                                    int2* __restrict__ edges, int E) {
    int e = blockIdx.x * 256 + threadIdx.x;
    if (e >= E) return;
    int pos = atomicAdd(&fill[rows[e]], 1);
    edges[pos] = make_int2(cols[e], __float_as_int(vals[e]));
}

// ---------------- aggregate: one wave/row, 8-edge unroll ----------------
__global__ __launch_bounds__(256) void spmm_rows(const unsigned short* __restrict__ S,
                                                 const int2* __restrict__ edges,
                                                 const int* __restrict__ ptr,
                                                 const float* __restrict__ bias,
                                                 float* __restrict__ out, int M) {
    const int row = blockIdx.x * 4 + (threadIdx.x >> 6);
    if (row >= M) return;
    const int lane = threadIdx.x & 63;
    float4 a0 = ((const float4*)bias)[lane];
    float4 a1 = make_float4(0.f, 0.f, 0.f, 0.f);
    float4 a2 = make_float4(0.f, 0.f, 0.f, 0.f);
    float4 a3 = make_float4(0.f, 0.f, 0.f, 0.f);
    const int beg = ptr[row];
    const int end = ptr[row + 1];
    int j = beg;
    const int end8 = beg + ((end - beg) & ~7);
    for (; j < end8; j += 8) {
        int4 p01 = *(const int4*)(edges + j);
        int4 p23 = *(const int4*)(edges + j + 2);
        int4 p45 = *(const int4*)(edges + j + 4);
        int4 p67 = *(const int4*)(edges + j + 6);
        ushort4 s0 = ((const ushort4*)(S + (size_t)p01.x * D_OUT))[lane];
        ushort4 s1 = ((const ushort4*)(S + (size_t)p01.z * D_OUT))[lane];
        ushort4 s2 = ((const ushort4*)(S + (size_t)p23.x * D_OUT))[lane];
        ushort4 s3 = ((const ushort4*)(S + (size_t)p23.z * D_OUT))[lane];
        ushort4 s4 = ((const ushort4*)(S + (size_t)p45.x * D_OUT))[lane];
        ushort4 s5 = ((const ushort4*)(S + (size_t)p45.z * D_OUT))[lane];
        ushort4 s6 = ((const ushort4*)(S + (size_t)p67.x * D_OUT))[lane];
        ushort4 s7 = ((const ushort4*)(S + (size_t)p67.z * D_OUT))[lane];
        float v0 = __int_as_float(p01.y), v1 = __int_as_float(p01.w);
        float v2 = __int_as_float(p23.y), v3 = __int_as_float(p23.w);
        float v4 = __int_as_float(p45.y), v5 = __int_as_float(p45.w);
        float v6 = __int_as_float(p67.y), v7 = __int_as_float(p67.w);
        a0.x += v0 * bf2f(s0.x) + v4 * bf2f(s4.x);
        a0.y += v0 * bf2f(s0.y) + v4 * bf2f(s4.y);
        a0.z += v0 * bf2f(s0.z) + v4 * bf2f(s4.z);
        a0.w += v0 * bf2f(s0.w) + v4 * bf2f(s4.w);
        a1.x += v1 * bf2f(s1.x) + v5 * bf2f(s5.x);
        a1.y += v1 * bf2f(s1.y) + v5 * bf2f(s5.y);
        a1.z += v1 * bf2f(s1.z) + v5 * bf2f(s5.z);
        a1.w += v1 * bf2f(s1.w) + v5 * bf2f(s5.w);
        a2.x += v2 * bf2f(s2.x) + v6 * bf2f(s6.x);
        a2.y += v2 * bf2f(s2.y) + v6 * bf2f(s6.y);
        a2.z += v2 * bf2f(s2.z) + v6 * bf2f(s6.z);
        a2.w += v2 * bf2f(s2.w) + v6 * bf2f(s6.w);
        a3.x += v3 * bf2f(s3.x) + v7 * bf2f(s7.x);
        a3.y += v3 * bf2f(s3.y) + v7 * bf2f(s7.y);
        a3.z += v3 * bf2f(s3.z) + v7 * bf2f(s7.z);
        a3.w += v3 * bf2f(s3.w) + v7 * bf2f(s7.w);
    }
    if (j + 3 < end) {
        int4 p01 = *(const int4*)(edges + j);
        int4 p23 = *(const int4*)(edges + j + 2);
        ushort4 s0 = ((const ushort4*)(S + (size_t)p01.x * D_OUT))[lane];
        ushort4 s1 = ((const ushort4*)(S + (size_t)p01.z * D_OUT))[lane];
        ushort4 s2 = ((const ushort4*)(S + (size_t)p23.x * D_OUT))[lane];
        ushort4 s3 = ((const ushort4*)(S + (size_t)p23.z * D_OUT))[lane];
        float v0 = __int_as_float(p01.y), v1 = __int_as_float(p01.w);
        float v2 = __int_as_float(p23.y), v3 = __int_as_float(p23.w);
        a0.x += v0 * bf2f(s0.x) + v2 * bf2f(s2.x);
        a0.y += v0 * bf2f(s0.y) + v2 * bf2f(s2.y);
        a0.z += v0 * bf2f(s0.z) + v2 * bf2f(s2.z);
        a0.w += v0 * bf2f(s0.w) + v2 * bf2f(s2.w);
        a1.x += v1 * bf2f(s1.x) + v3 * bf2f(s3.x);
        a1.y += v1 * bf2f(s1.y) + v3 * bf2f(s3.y);
        a1.z += v1 * bf2f(s1.z) + v3 * bf2f(s3.z);
        a1.w += v1 * bf2f(s1.w) + v3 * bf2f(s3.w);
        j += 4;
    }
    for (; j < end; ++j) {
        int2 e = edges[j];
        float v = __int_as_float(e.y);
        ushort4 s = ((const ushort4*)(S + (size_t)e.x * D_OUT))[lane];
        a0.x += v * bf2f(s.x);
        a0.y += v * bf2f(s.y);
        a0.z += v * bf2f(s.z);
        a0.w += v * bf2f(s.w);
    }
    a0.x += a1.x + a2.x + a3.x;
    a0.y += a1.y + a2.y + a3.y;
    a0.z += a1.z + a2.z + a3.z;
    a0.w += a1.w + a2.w + a3.w;
    ((float4*)out)[(size_t)row * 64 + lane] = a0;
}

extern "C" void kernel_launch(void* const* d_in, const int* in_sizes, int n_in,
                              void* d_out, int out_size, void* d_ws, size_t ws_size,
                              hipStream_t stream) {
    const float* inputs    = (const float*)d_in[0];
    const float* weights   = (const float*)d_in[1];
    const float* bias      = (const float*)d_in[2];
    const float* edge_vals = (const float*)d_in[3];
    const int*   edge_row  = (const int*)d_in[4];
    const int*   edge_col  = (const int*)d_in[5];
    float* out = (float*)d_out;

    const int M = in_sizes[0] / D_IN;  // 50000
    const int E = in_sizes[3];         // 800000

    char* ws = (char*)d_ws;
    unsigned short* S  = (unsigned short*)ws;
    unsigned short* Wt = (unsigned short*)(ws + (size_t)M * D_OUT * 2);
    int2* edges        = (int2*)((char*)Wt + (size_t)D_OUT * D_IN * 2);
    int*  ptr          = (int*)((char*)edges + (size_t)E * 8);
    int*  cnt          = ptr + ((M + 4) & ~3);
    int*  fill         = cnt + ((M + 4) & ~3);

    // 1) convert W + zero cnt
    prep<<<512 + (M + 255) / 256, 256, 0, stream>>>(weights, Wt, cnt, M);

    // 2) gemm (separate dispatch; r5 showed hist-fusion costs 40us)
    dim3 ggrid((M + 127) / 128, D_OUT / 128);
    gemm_bf16<<<ggrid, 512, 0, stream>>>(inputs, Wt, S, M);

    // 3) histogram
    int E4 = E / 4;
    hist_rows<<<(E4 + 255) / 256, 256, 0, stream>>>(edge_row, cnt, E4);

    // 4) exclusive scan -> ptr, fill
    scan_rowptr<<<1, 1024, 0, stream>>>(cnt, ptr, fill, M);

    // 5) place edges
    build_sorted<<<(E + 255) / 256, 256, 0, stream>>>(edge_vals, edge_row, edge_col,
                                                      fill, edges, E);

    // 6) aggregate
    spmm_rows<<<(M + 3) / 4, 256, 0, stream>>>(S, edges, ptr, bias, out, M);
}